// Round 2
// baseline (1851.579 us; speedup 1.0000x reference)
//
#include <hip/hip_runtime.h>
#include <math.h>

#define MAX_ITER 20
#define EPS_W 1e-3f
#define CLAMP_MIN 1e-4f
#define CLAMP_MAX 1e4f

// softplus -> +eps -> clip  (matches jax.nn.softplus = logaddexp(x,0))
__device__ __forceinline__ float sp_w(float u) {
    float sp = fmaxf(u, 0.f) + log1pf(expf(-fabsf(u)));
    float w = sp + EPS_W;
    return fminf(fmaxf(w, CLAMP_MIN), CLAMP_MAX);
}
__device__ __forceinline__ float nn(float x) { return (x == x) ? x : 0.f; }

// valid only on threadIdx.x == 0 ; block size must be 256 (4 waves)
__device__ __forceinline__ float blockReduceSum(float v) {
    #pragma unroll
    for (int off = 32; off > 0; off >>= 1) v += __shfl_down(v, off, 64);
    __shared__ float smem[4];
    int lane = threadIdx.x & 63, wid = threadIdx.x >> 6;
    if (lane == 0) smem[wid] = v;
    __syncthreads();
    float r = 0.f;
    if (threadIdx.x == 0) r = smem[0] + smem[1] + smem[2] + smem[3];
    return r;
}

__global__ __launch_bounds__(256) void k_scatter(const int* __restrict__ idx,
                                                 int* __restrict__ pos, int K) {
    int k = blockIdx.x * 256 + threadIdx.x;
    if (k < K) pos[idx[k]] = k;
}

// w output: elementwise over flat B*m (divisible by 4)
__global__ __launch_bounds__(256) void k_w(const float* __restrict__ u,
                                           float* __restrict__ w, int total4) {
    int t = blockIdx.x * 256 + threadIdx.x;
    if (t >= total4) return;
    float4 uu = reinterpret_cast<const float4*>(u)[t];
    float4 ww;
    ww.x = sp_w(uu.x); ww.y = sp_w(uu.y); ww.z = sp_w(uu.z); ww.w = sp_w(uu.w);
    reinterpret_cast<float4*>(w)[t] = ww;
}

// init: dg, cl, rhs, v=0, rcg=p0=rhs, rs0 = ||rhs||^2 per batch
__global__ __launch_bounds__(256) void k_init(const int* __restrict__ idx,
                                              const float* __restrict__ u,
                                              const float* __restrict__ x,
                                              float* __restrict__ v,
                                              float* __restrict__ rg,
                                              float* __restrict__ p0,
                                              float* __restrict__ dg,
                                              float* __restrict__ cl,
                                              float* __restrict__ rs_arr,
                                              int n, int K) {
    int g = blockIdx.x * 256 + threadIdx.x;  // g < B*K, K multiple of 256
    int b = g / K;
    int k = g - b * K;
    int m = n - 1;
    int j = idx[k];
    bool la = (k > 0) && (idx[k - 1] == j - 1);
    bool ra = (k < K - 1) && (idx[k + 1] == j + 1);
    const float* ub = u + (size_t)b * m;
    const float* xb = x + (size_t)b * n;
    float wl = 0.f, wr = 0.f;
    if (j >= 1)     { float w = sp_w(ub[j - 1]); wl = w * w; }
    if (j <= n - 2) { float w = sp_w(ub[j]);     wr = w * w; }
    float rhs = 0.f;
    if (j >= 1 && !la)     rhs += wl * nn(xb[j - 1]);
    if (j <= n - 2 && !ra) rhs += wr * nn(xb[j + 1]);
    v[g]  = 0.f;
    rg[g] = rhs;
    p0[g] = rhs;
    dg[g] = wl + wr;
    cl[g] = la ? wl : 0.f;
    float s = blockReduceSum(rhs * rhs);
    if (threadIdx.x == 0) atomicAdd(&rs_arr[b], s);
}

// CG kernel A: p_new = rcg + beta*p_old (halo recomputed), Kp = K(p_new),
// accumulate p_new . Kp into pkp_arr[iter*B+b]
__global__ __launch_bounds__(256) void k_cg_a(const float* __restrict__ rg,
                                              const float* __restrict__ p_old,
                                              float* __restrict__ p_new,
                                              float* __restrict__ kp,
                                              const float* __restrict__ dg,
                                              const float* __restrict__ cl,
                                              const float* __restrict__ rs_arr,
                                              float* __restrict__ pkp_arr,
                                              int iter, int B, int K) {
    int t = blockIdx.x * 256 + threadIdx.x;
    int g = t * 4;
    int total = B * K;
    int b = g / K;  // block fully within one batch (K % 1024 == 0)
    float beta = (iter == 0) ? 0.f
               : rs_arr[iter * B + b] / (rs_arr[(iter - 1) * B + b] + 1e-30f);
    float4 rc = reinterpret_cast<const float4*>(rg)[t];
    float4 po = reinterpret_cast<const float4*>(p_old)[t];
    float4 dd = reinterpret_cast<const float4*>(dg)[t];
    float4 cc = reinterpret_cast<const float4*>(cl)[t];
    float rcm = (g > 0) ? rg[g - 1] : 0.f;
    float pom = (g > 0) ? p_old[g - 1] : 0.f;
    bool tail = (g + 4 < total);
    float rcp = tail ? rg[g + 4] : 0.f;
    float pop = tail ? p_old[g + 4] : 0.f;
    float ccp = tail ? cl[g + 4] : 0.f;  // cross-batch reads hit cl[...][0]==0 -> harmless
    float pn[6];
    pn[0] = rcm + beta * pom;
    pn[1] = rc.x + beta * po.x;
    pn[2] = rc.y + beta * po.y;
    pn[3] = rc.z + beta * po.z;
    pn[4] = rc.w + beta * po.w;
    pn[5] = rcp + beta * pop;
    float c[5] = {cc.x, cc.y, cc.z, cc.w, ccp};
    float d4[4] = {dd.x, dd.y, dd.z, dd.w};
    float kv[4];
    float dot = 0.f;
    #pragma unroll
    for (int i = 0; i < 4; ++i) {
        kv[i] = d4[i] * pn[i + 1] - c[i] * pn[i] - c[i + 1] * pn[i + 2];
        dot += pn[i + 1] * kv[i];
    }
    reinterpret_cast<float4*>(p_new)[t] = make_float4(pn[1], pn[2], pn[3], pn[4]);
    reinterpret_cast<float4*>(kp)[t]    = make_float4(kv[0], kv[1], kv[2], kv[3]);
    float s = blockReduceSum(dot);
    if (threadIdx.x == 0) atomicAdd(&pkp_arr[iter * B + b], s);
}

// CG kernel B: alpha, v += alpha p, rcg -= alpha Kp, rs_{iter+1} = ||rcg||^2
__global__ __launch_bounds__(256) void k_cg_b(float* __restrict__ v,
                                              float* __restrict__ rg,
                                              const float* __restrict__ p_new,
                                              const float* __restrict__ kp,
                                              float* __restrict__ rs_arr,
                                              const float* __restrict__ pkp_arr,
                                              int iter, int B, int K) {
    int t = blockIdx.x * 256 + threadIdx.x;
    int g = t * 4;
    int b = g / K;
    float alpha = rs_arr[iter * B + b] / (pkp_arr[iter * B + b] + 1e-30f);
    float4 pv = reinterpret_cast<const float4*>(p_new)[t];
    float4 kv = reinterpret_cast<const float4*>(kp)[t];
    float4 vv = reinterpret_cast<float4*>(v)[t];
    float4 rv = reinterpret_cast<float4*>(rg)[t];
    vv.x += alpha * pv.x; vv.y += alpha * pv.y; vv.z += alpha * pv.z; vv.w += alpha * pv.w;
    rv.x -= alpha * kv.x; rv.y -= alpha * kv.y; rv.z -= alpha * kv.z; rv.w -= alpha * kv.w;
    reinterpret_cast<float4*>(v)[t]  = vv;
    reinterpret_cast<float4*>(rg)[t] = rv;
    float dot = rv.x * rv.x + rv.y * rv.y + rv.z * rv.z + rv.w * rv.w;
    float s = blockReduceSum(dot);
    if (threadIdx.x == 0) atomicAdd(&rs_arr[(iter + 1) * B + b], s);
}

// final: r = D(x_known + scatter(v)), phi = sum w^2 r^2
__global__ __launch_bounds__(256) void k_final(const float* __restrict__ x,
                                               const float* __restrict__ w_out,
                                               const int* __restrict__ pos,
                                               const float* __restrict__ v,
                                               float* __restrict__ r_out,
                                               float* __restrict__ phi,
                                               int n, int K) {
    int m = n - 1;
    int b = blockIdx.y;
    int i0 = (blockIdx.x * 256 + threadIdx.x) * 4;
    const float* xb = x + (size_t)b * n;
    const float* wb = w_out + (size_t)b * m;
    const float* vb = v + (size_t)b * K;
    float* rb = r_out + (size_t)b * m;
    float sv[5];
    #pragma unroll
    for (int q = 0; q < 5; ++q) {
        int i = i0 + q;
        if (i <= m) {
            int p = pos[i];
            sv[q] = (p >= 0) ? vb[p] : nn(xb[i]);
        } else sv[q] = 0.f;
    }
    float acc = 0.f;
    #pragma unroll
    for (int q = 0; q < 4; ++q) {
        int i = i0 + q;
        if (i < m) {
            float r = sv[q + 1] - sv[q];
            rb[i] = r;
            float w = wb[i];
            acc += w * w * r * r;
        }
    }
    float s = blockReduceSum(acc);
    if (threadIdx.x == 0) atomicAdd(&phi[b], s);
}

extern "C" void kernel_launch(void* const* d_in, const int* in_sizes, int n_in,
                              void* d_out, int out_size, void* d_ws, size_t ws_size,
                              hipStream_t stream) {
    const float* u  = (const float*)d_in[0];  // [B, n-1]
    const float* x  = (const float*)d_in[1];  // [B, n]
    const int* idx  = (const int*)d_in[2];    // [K]

    const int B = 16;
    const int n = in_sizes[1] / B;   // 262144
    const int m = n - 1;             // 262143
    const int K = in_sizes[2];       // 131072
    const int NK = B * K;            // 2097152

    float* out   = (float*)d_out;
    float* phi   = out;                         // [B]
    float* v_out = out + B;                     // [B,K]
    float* r_out = v_out + (size_t)B * K;       // [B,m]
    float* w_out = r_out + (size_t)B * m;       // [B,m]

    char* ws = (char*)d_ws;
    float* v  = (float*)ws;              ws += sizeof(float) * (size_t)NK;
    float* rg = (float*)ws;              ws += sizeof(float) * (size_t)NK;
    float* p0 = (float*)ws;              ws += sizeof(float) * (size_t)NK;
    float* p1 = (float*)ws;              ws += sizeof(float) * (size_t)NK;
    float* kp = (float*)ws;              ws += sizeof(float) * (size_t)NK;
    float* dg = (float*)ws;              ws += sizeof(float) * (size_t)NK;
    float* cl = (float*)ws;              ws += sizeof(float) * (size_t)NK;
    float* rs_arr  = (float*)ws;         ws += sizeof(float) * (MAX_ITER + 1) * B;
    float* pkp_arr = (float*)ws;         ws += sizeof(float) * MAX_ITER * B;
    int*   pos = (int*)ws;               ws += sizeof(int) * (size_t)n;

    // reset per-call accumulators (graph replays must be idempotent)
    hipMemsetAsync(rs_arr, 0, sizeof(float) * ((MAX_ITER + 1) * B + MAX_ITER * B), stream);
    hipMemsetAsync(pos, 0xFF, sizeof(int) * (size_t)n, stream);  // -1
    hipMemsetAsync(phi, 0, sizeof(float) * B, stream);

    k_scatter<<<(K + 255) / 256, 256, 0, stream>>>(idx, pos, K);

    int tot4w = (B * m) / 4;  // B*m divisible by 4 (B=16)
    k_w<<<(tot4w + 255) / 256, 256, 0, stream>>>(u, w_out, tot4w);

    k_init<<<NK / 256, 256, 0, stream>>>(idx, u, x, v, rg, p0, dg, cl, rs_arr, n, K);

    float* pb[2] = {p0, p1};
    for (int it = 0; it < MAX_ITER; ++it) {
        k_cg_a<<<NK / 1024, 256, 0, stream>>>(rg, pb[it & 1], pb[(it + 1) & 1], kp,
                                              dg, cl, rs_arr, pkp_arr, it, B, K);
        k_cg_b<<<NK / 1024, 256, 0, stream>>>(v, rg, pb[(it + 1) & 1], kp,
                                              rs_arr, pkp_arr, it, B, K);
    }

    k_final<<<dim3((m + 1023) / 1024, B), 256, 0, stream>>>(x, w_out, pos, v, r_out, phi, n, K);

    hipMemcpyAsync(v_out, v, sizeof(float) * (size_t)NK, hipMemcpyDeviceToDevice, stream);
}